// Round 5
// baseline (845.675 us; speedup 1.0000x reference)
//
#include <hip/hip_runtime.h>
#include <cstdint>
#include <cstddef>

#define TT    100
#define MROWS 200      // T*C real rows
#define KDIM  16384    // H*W
#define DDIM  8192     // hypervector dim
#define KSL   16       // K slices (grid.z)
#define KPER  (KDIM / KSL)   // 1024

typedef __bf16 bf16x8 __attribute__((ext_vector_type(8)));
typedef float  f32x4  __attribute__((ext_vector_type(4)));

// ---------------------------------------------------------------------------
// Zero d_out (poisoned 0xAA before every timed launch).
// ---------------------------------------------------------------------------
__global__ __launch_bounds__(256) void zero_kernel(float* __restrict__ out) {
    out[blockIdx.x * 256 + threadIdx.x] = 0.f;
}

// ---------------------------------------------------------------------------
// Split 8 fp32 -> hi/lo bf16 planes, packed k-contiguous (2 shorts/dword).
// hi = round-half-up on mantissa bit 15 (<=0.5 ulp); lo = rn(v - hi), exact
// subtraction; recombined product exact to ~2^-16 relative.
// ---------------------------------------------------------------------------
static __device__ __forceinline__ void split_row(const float4 a, const float4 b,
                                                 uint4& hi, uint4& lo) {
    const float v[8] = {a.x, a.y, a.z, a.w, b.x, b.y, b.z, b.w};
    unsigned int h[8];
    unsigned int m[8];
#pragma unroll
    for (int i = 0; i < 8; ++i) {
        unsigned int u = __float_as_uint(v[i]);
        h[i] = (u + 0x8000u) & 0xFFFF0000u;            // rounded hi bits
        float l = v[i] - __uint_as_float(h[i]);        // exact
        m[i] = (__float_as_uint(l) + 0x8000u) & 0xFFFF0000u;
    }
    hi.x = (h[0] >> 16) | h[1];  hi.y = (h[2] >> 16) | h[3];
    hi.z = (h[4] >> 16) | h[5];  hi.w = (h[6] >> 16) | h[7];
    lo.x = (m[0] >> 16) | m[1];  lo.y = (m[2] >> 16) | m[3];
    lo.z = (m[4] >> 16) | m[5];  lo.w = (m[6] >> 16) | m[7];
}

// ---------------------------------------------------------------------------
// Fused GEMM + bind-reduce, 128x128x32 tile, register-double-buffered.
//   gesture[d] = sum_{m<200,k} hist[m,k] * pos[k,d] * time_w[m>>1,d] * pol_w[m&1,d]
// K-loop (m97 barrier-drain aware):
//   [barrier1; write packed regs->LDS; barrier2; ISSUE next loads;
//    frag reads + MFMA; convert next loads -> packed regs]
// Global loads are in flight across the whole MFMA phase; no vmem pending at
// either barrier. B staged as two n-quads per thread (4bq+j and 64+4bq+j):
// full 128-col coverage (round-4 bug: only 64) and 2-way write banks (free).
// Zero d_ws usage (round-1 ws pipeline corrupted harness state on replay).
// ---------------------------------------------------------------------------
__global__ __launch_bounds__(256, 2) void gemm_kernel(const float* __restrict__ hist,
                                                      const float* __restrict__ pos,
                                                      const float* __restrict__ time_w,
                                                      const float* __restrict__ pol_w,
                                                      float* __restrict__ out) {
    __shared__ alignas(16) unsigned short As[2][128][32];  // [plane][m][k] 16 KB
    __shared__ alignas(16) unsigned short Bs[128][40];     // [n][k], 80 B rows 10 KB
    __shared__ float sPart[128];

    const int t     = threadIdx.x;
    const int n0    = blockIdx.x * 128;
    const int m0    = blockIdx.y * 128;
    const int kbase = blockIdx.z * KPER;

    const int lane = t & 63;
    const int wv   = t >> 6;
    const int wm   = (wv & 1) * 64;    // wave m offset (2x2 wave grid)
    const int wn   = (wv >> 1) * 64;   // wave n offset
    const int l15  = lane & 15;
    const int q8   = (lane >> 4) * 8;  // k offset within fragment

    if (t < 128) sPart[t] = 0.f;       // visible after first __syncthreads

    // A staging: thread -> rows (ar, ar+64), 8 consecutive k.
    const int ar  = t >> 2;            // 0..63
    const int akb = (t & 3) * 8;       // 0,8,16,24
    const bool v0 = (m0 + ar)      < MROWS;
    const bool v1 = (m0 + ar + 64) < MROWS;
    const float* gA0 = hist + (size_t)(m0 + ar)      * KDIM + akb + kbase;
    const float* gA1 = hist + (size_t)(m0 + ar + 64) * KDIM + akb + kbase;

    // B staging: thread -> k-pair bp (rows 2bp,2bp+1) x n-quads {4bq, 64+4bq}.
    const int bp = t & 15;             // k-pair 0..15
    const int bq = t >> 4;             // n-quad 0..15
    const float* gB0 = pos + ((size_t)kbase + 2 * bp)     * DDIM + n0 + 4 * bq;
    const float* gB1 = pos + ((size_t)kbase + 2 * bp + 1) * DDIM + n0 + 4 * bq;

    f32x4 acc[4][4];
#pragma unroll
    for (int s = 0; s < 4; ++s)
#pragma unroll
        for (int j = 0; j < 4; ++j) acc[s][j] = (f32x4){0.f, 0.f, 0.f, 0.f};

    // ---- prologue: load k=0, convert ----
    float4 a00 = {0,0,0,0}, a01 = {0,0,0,0}, a10 = {0,0,0,0}, a11 = {0,0,0,0};
    if (v0) { a00 = *(const float4*)(gA0);     a01 = *(const float4*)(gA0 + 4); }
    if (v1) { a10 = *(const float4*)(gA1);     a11 = *(const float4*)(gA1 + 4); }
    float4 bx0 = *(const float4*)(gB0);
    float4 bx1 = *(const float4*)(gB0 + 64);
    float4 by0 = *(const float4*)(gB1);
    float4 by1 = *(const float4*)(gB1 + 64);

    uint4 wAh0, wAl0, wAh1, wAl1;
    unsigned int wB[8];
    split_row(a00, a01, wAh0, wAl0);
    split_row(a10, a11, wAh1, wAl1);
    {
        const float x0[4] = {bx0.x, bx0.y, bx0.z, bx0.w};
        const float x1[4] = {bx1.x, bx1.y, bx1.z, bx1.w};
        const float y0[4] = {by0.x, by0.y, by0.z, by0.w};
        const float y1[4] = {by1.x, by1.y, by1.z, by1.w};
#pragma unroll
        for (int j = 0; j < 4; ++j) {
            wB[j]     = (__float_as_uint(x0[j]) >> 16) |
                        (__float_as_uint(y0[j]) & 0xFFFF0000u);   // exact: +/-1
            wB[4 + j] = (__float_as_uint(x1[j]) >> 16) |
                        (__float_as_uint(y1[j]) & 0xFFFF0000u);
        }
    }

    for (int kk = 0; kk < KPER; kk += 32) {
        __syncthreads();   // barrier1: previous frag reads done (no vmem pending)

        *(uint4*)&As[0][ar][akb]      = wAh0;
        *(uint4*)&As[1][ar][akb]      = wAl0;
        *(uint4*)&As[0][ar + 64][akb] = wAh1;
        *(uint4*)&As[1][ar + 64][akb] = wAl1;
#pragma unroll
        for (int j = 0; j < 4; ++j) {
            *(unsigned int*)&Bs[4 * bq + j][2 * bp]      = wB[j];
            *(unsigned int*)&Bs[64 + 4 * bq + j][2 * bp] = wB[4 + j];
        }

        __syncthreads();   // barrier2: tile visible (drains only LDS writes)

        // ---- issue prefetch for next k-step (in flight during MFMA) ----
        const int kn = (kk + 32 < KPER) ? kk + 32 : 0;   // wrap: harmless L2 hit
        a00 = (float4){0,0,0,0}; a01 = a00; a10 = a00; a11 = a00;
        if (v0) { a00 = *(const float4*)(gA0 + kn);     a01 = *(const float4*)(gA0 + kn + 4); }
        if (v1) { a10 = *(const float4*)(gA1 + kn);     a11 = *(const float4*)(gA1 + kn + 4); }
        bx0 = *(const float4*)(gB0 + (size_t)kn * DDIM);
        bx1 = *(const float4*)(gB0 + (size_t)kn * DDIM + 64);
        by0 = *(const float4*)(gB1 + (size_t)kn * DDIM);
        by1 = *(const float4*)(gB1 + (size_t)kn * DDIM + 64);

        // ---- fragments + MFMA ----
        uint4 fa0[4], fa1[4], fb[4];
#pragma unroll
        for (int s = 0; s < 4; ++s) {
            fa0[s] = *(const uint4*)&As[0][wm + s * 16 + l15][q8];
            fa1[s] = *(const uint4*)&As[1][wm + s * 16 + l15][q8];
        }
#pragma unroll
        for (int j = 0; j < 4; ++j)
            fb[j] = *(const uint4*)&Bs[wn + j * 16 + l15][q8];

#pragma unroll
        for (int s = 0; s < 4; ++s)
#pragma unroll
            for (int j = 0; j < 4; ++j) {
                acc[s][j] = __builtin_amdgcn_mfma_f32_16x16x32_bf16(
                    __builtin_bit_cast(bf16x8, fa0[s]),
                    __builtin_bit_cast(bf16x8, fb[j]), acc[s][j], 0, 0, 0);
                acc[s][j] = __builtin_amdgcn_mfma_f32_16x16x32_bf16(
                    __builtin_bit_cast(bf16x8, fa1[s]),
                    __builtin_bit_cast(bf16x8, fb[j]), acc[s][j], 0, 0, 0);
            }

        // ---- convert prefetched data (vmcnt waits here, a full MFMA phase
        //      after issue) ----
        split_row(a00, a01, wAh0, wAl0);
        split_row(a10, a11, wAh1, wAl1);
        {
            const float x0[4] = {bx0.x, bx0.y, bx0.z, bx0.w};
            const float x1[4] = {bx1.x, bx1.y, bx1.z, bx1.w};
            const float y0[4] = {by0.x, by0.y, by0.z, by0.w};
            const float y1[4] = {by1.x, by1.y, by1.z, by1.w};
#pragma unroll
            for (int j = 0; j < 4; ++j) {
                wB[j]     = (__float_as_uint(x0[j]) >> 16) |
                            (__float_as_uint(y0[j]) & 0xFFFF0000u);
                wB[4 + j] = (__float_as_uint(x1[j]) >> 16) |
                            (__float_as_uint(y1[j]) & 0xFFFF0000u);
            }
        }
    }

    // Epilogue: C/D layout col = lane&15, row = (lane>>4)*4 + reg (m89/m91).
    const int qrow = (lane >> 4) * 4;
#pragma unroll
    for (int j = 0; j < 4; ++j) {
        const int col = wn + j * 16 + l15;     // 0..127 within tile
        const int d   = n0 + col;
        const float p0 = pol_w[d];
        const float p1 = pol_w[DDIM + d];
        float part = 0.f;
#pragma unroll
        for (int s = 0; s < 4; ++s)
#pragma unroll
            for (int r = 0; r < 4; ++r) {
                const int m = m0 + wm + s * 16 + qrow + r;
                if (m < MROWS) {
                    const int tt_ = m >> 1;
                    const float w = time_w[(size_t)tt_ * DDIM + d] *
                                    ((m & 1) ? p1 : p0);
                    part += w * acc[s][j][r];
                }
            }
        atomicAdd(&sPart[col], part);
    }
    __syncthreads();
    if (t < 128) atomicAdd(out + n0 + t, sPart[t]);
}

// ---------------------------------------------------------------------------
// Final: out[d] = sign(out[d]) in place.
// ---------------------------------------------------------------------------
__global__ __launch_bounds__(256) void sign_kernel(float* __restrict__ out) {
    int d = blockIdx.x * 256 + threadIdx.x;
    float s = out[d];
    out[d] = (s > 0.f) ? 1.f : ((s < 0.f) ? -1.f : 0.f);
}

// ---------------------------------------------------------------------------
extern "C" void kernel_launch(void* const* d_in, const int* in_sizes, int n_in,
                              void* d_out, int out_size, void* d_ws, size_t ws_size,
                              hipStream_t stream) {
    const float* hist   = (const float*)d_in[0];   // [100,2,128,128]
    const float* time_w = (const float*)d_in[1];   // [100,8192]
    const float* pol_w  = (const float*)d_in[2];   // [2,8192]
    const float* pos_w  = (const float*)d_in[3];   // [16384,8192]
    float* out = (float*)d_out;                    // [8192]
    (void)d_ws; (void)ws_size;                     // zero workspace used

    zero_kernel<<<DDIM / 256, 256, 0, stream>>>(out);
    gemm_kernel<<<dim3(DDIM / 128, 2, KSL), 256, 0, stream>>>(hist, pos_w, time_w, pol_w, out);
    sign_kernel<<<DDIM / 256, 256, 0, stream>>>(out);
}